// Round 1
// baseline (272.222 us; speedup 1.0000x reference)
//
#include <hip/hip_runtime.h>
#include <hip/hip_bf16.h>
#include <stdint.h>

#define EMB   2048
#define TOK   2048
#define NH    32
#define NKV   8
#define HD    64
#define QKVN  3072   // 2048 q + 512 k + 512 v

typedef __attribute__((ext_vector_type(8))) short bf16x8;  // 8 bf16 = 4 VGPRs
typedef __attribute__((ext_vector_type(4))) float f32x4;

__device__ __forceinline__ void gld16(const void* g, void* l) {
  auto gp = reinterpret_cast<const int __attribute__((address_space(1)))*>(
      reinterpret_cast<uintptr_t>(g));
  auto lp = reinterpret_cast<int __attribute__((address_space(3)))*>(
      reinterpret_cast<uintptr_t>(l));
  __builtin_amdgcn_global_load_lds(gp, lp, 16, 0, 0);
}

// ---------------------------------------------------------------- cast fp32->bf16
// layout: [x 4M][Wq 4M -> Wc rows 0..2047][Wk 1M -> Wc rows 2048..2559]
//         [Wv 1M -> Wc rows 2560..3071][Wo 4M -> Wob]
__global__ void cast_all(const float* __restrict__ x,  const float* __restrict__ wq,
                         const float* __restrict__ wk, const float* __restrict__ wv,
                         const float* __restrict__ wo,
                         __hip_bfloat16* __restrict__ xb,
                         __hip_bfloat16* __restrict__ wc,
                         __hip_bfloat16* __restrict__ wob) {
  const size_t M4 = (size_t)4 * 1024 * 1024;
  const size_t M1 = (size_t)1024 * 1024;
  size_t i = ((size_t)blockIdx.x * 256 + threadIdx.x) * 4;
  const float* src;
  __hip_bfloat16* dst;
  if (i < M4)                    { src = x  + i;                 dst = xb  + i; }
  else if (i < 2*M4)             { src = wq + (i - M4);          dst = wc  + (i - M4); }
  else if (i < 2*M4 + M1)        { src = wk + (i - 2*M4);        dst = wc  + M4 + (i - 2*M4); }
  else if (i < 2*M4 + 2*M1)      { src = wv + (i - 2*M4 - M1);   dst = wc  + M4 + M1 + (i - 2*M4 - M1); }
  else                           { src = wo + (i - 2*M4 - 2*M1); dst = wob + (i - 2*M4 - 2*M1); }
  float4 v = *reinterpret_cast<const float4*>(src);
  dst[0] = __float2bfloat16(v.x);
  dst[1] = __float2bfloat16(v.y);
  dst[2] = __float2bfloat16(v.z);
  dst[3] = __float2bfloat16(v.w);
}

// ---------------------------------------------------------------- GEMM  C = A * B^T
// A: M x K bf16 row-major, B: N x K bf16 row-major, C: M x N fp32.
// 128x128 tile, BK=64, 256 threads (4 waves, 2x2), m97 structure.
__global__ __launch_bounds__(256) void gemm_bt(const __hip_bfloat16* __restrict__ A,
                                               const __hip_bfloat16* __restrict__ B,
                                               float* __restrict__ C,
                                               int M, int N, int K) {
  __shared__ __hip_bfloat16 As[128 * 64];
  __shared__ __hip_bfloat16 Bs[128 * 64];
  const int nbc = N >> 7;
  const int br  = blockIdx.x / nbc;
  const int bc  = blockIdx.x % nbc;
  const int tid  = threadIdx.x;
  const int lane = tid & 63;
  const int w    = tid >> 6;
  const int wr   = w >> 1, wc = w & 1;
  const int l15  = lane & 15;
  const int fk   = (lane >> 4) << 3;

  f32x4 acc[4][4];
#pragma unroll
  for (int m = 0; m < 4; ++m)
#pragma unroll
    for (int n = 0; n < 4; ++n) acc[m][n] = (f32x4){0.f, 0.f, 0.f, 0.f};

  const __hip_bfloat16* Ag = A + (size_t)br * 128 * K;
  const __hip_bfloat16* Bg = B + (size_t)bc * 128 * K;

  // staging geometry: chunk c = w*4+r holds LDS bytes [c*1024, c*1024+1024)
  int srow[4], scol[4];
#pragma unroll
  for (int r = 0; r < 4; ++r) {
    int o = (w * 4 + r) * 1024 + lane * 16;
    srow[r] = o >> 7;          // row within 128-row tile (row stride 128 B)
    scol[r] = (o & 127) >> 1;  // bf16 col within 64-col K-slab
  }

  for (int kt = 0; kt < K; kt += 64) {
#pragma unroll
    for (int r = 0; r < 4; ++r) {
      const int c = w * 4 + r;
      gld16(Ag + (size_t)srow[r] * K + kt + scol[r], (char*)As + c * 1024);
      gld16(Bg + (size_t)srow[r] * K + kt + scol[r], (char*)Bs + c * 1024);
    }
    __syncthreads();  // drains vmcnt (global_load_lds) per compiler barrier semantics

    bf16x8 a[4][2], b[4][2];
#pragma unroll
    for (int m = 0; m < 4; ++m)
#pragma unroll
      for (int kk = 0; kk < 2; ++kk)
        a[m][kk] = *reinterpret_cast<const bf16x8*>(
            (const char*)As + ((wr * 64 + m * 16 + l15) * 64 + kk * 32 + fk) * 2);
#pragma unroll
    for (int n = 0; n < 4; ++n)
#pragma unroll
      for (int kk = 0; kk < 2; ++kk)
        b[n][kk] = *reinterpret_cast<const bf16x8*>(
            (const char*)Bs + ((wc * 64 + n * 16 + l15) * 64 + kk * 32 + fk) * 2);

#pragma unroll
    for (int m = 0; m < 4; ++m)
#pragma unroll
      for (int n = 0; n < 4; ++n)
#pragma unroll
        for (int kk = 0; kk < 2; ++kk)
          acc[m][n] = __builtin_amdgcn_mfma_f32_16x16x32_bf16(a[m][kk], b[n][kk],
                                                              acc[m][n], 0, 0, 0);
    __syncthreads();
  }

  const int row0 = br * 128 + wr * 64;
  const int col0 = bc * 128 + wc * 64;
  const int rb   = (lane >> 4) * 4;
#pragma unroll
  for (int m = 0; m < 4; ++m)
#pragma unroll
    for (int n = 0; n < 4; ++n)
#pragma unroll
      for (int r = 0; r < 4; ++r)
        C[(size_t)(row0 + m * 16 + rb + r) * N + col0 + n * 16 + l15] = acc[m][n][r];
}

// ---------------------------------------------------------------- RoPE + cast + V transpose
// qkv fp32 [TOK][3072] -> Qb bf16 [NH][TOK][HD], Kb bf16 [NKV][TOK][HD],
//                         Vt bf16 [NKV][HD][TOK]  (transposed for PV B-operand)
__global__ void rope_cast(const float* __restrict__ qkv,
                          const float* __restrict__ cosT, const float* __restrict__ sinT,
                          __hip_bfloat16* __restrict__ Qb,
                          __hip_bfloat16* __restrict__ Kb,
                          __hip_bfloat16* __restrict__ Vt) {
  const int QP = TOK * NH * (HD / 2);   // 2,097,152
  const int KP = TOK * NKV * (HD / 2);  //   524,288
  int idx = blockIdx.x * 256 + threadIdx.x;
  if (idx < QP) {
    int d = idx & 31, h = (idx >> 5) & 31, t = idx >> 10;
    const float* row = qkv + (size_t)t * QKVN + h * 64;
    float x1 = row[d], x2 = row[d + 32];
    float o1 = x1 * cosT[t * 64 + d]      - x2 * sinT[t * 64 + d];
    float o2 = x2 * cosT[t * 64 + d + 32] + x1 * sinT[t * 64 + d + 32];
    __hip_bfloat16* q = Qb + ((size_t)h * TOK + t) * HD;
    q[d]      = __float2bfloat16(o1);
    q[d + 32] = __float2bfloat16(o2);
  } else if (idx < QP + KP) {
    int j = idx - QP;
    int d = j & 31, h = (j >> 5) & 7, t = j >> 8;
    const float* row = qkv + (size_t)t * QKVN + 2048 + h * 64;
    float x1 = row[d], x2 = row[d + 32];
    float o1 = x1 * cosT[t * 64 + d]      - x2 * sinT[t * 64 + d];
    float o2 = x2 * cosT[t * 64 + d + 32] + x1 * sinT[t * 64 + d + 32];
    __hip_bfloat16* k = Kb + ((size_t)h * TOK + t) * HD;
    k[d]      = __float2bfloat16(o1);
    k[d + 32] = __float2bfloat16(o2);
  } else {
    int j = idx - QP - KP;                // j = hk*HD*TOK + d*TOK + t (coalesced writes)
    int t = j & (TOK - 1), d = (j >> 11) & 63, hk = j >> 17;
    float v = qkv[(size_t)t * QKVN + 2560 + hk * 64 + d];
    Vt[(size_t)j] = __float2bfloat16(v);
  }
}

// ---------------------------------------------------------------- causal GQA flash attention
// grid = 32 qtiles * 32 heads; block = 256 (4 waves, each owns 16 q-rows)
__global__ __launch_bounds__(256) void attn(const __hip_bfloat16* __restrict__ Qb,
                                            const __hip_bfloat16* __restrict__ Kb,
                                            const __hip_bfloat16* __restrict__ Vt,
                                            __hip_bfloat16* __restrict__ ctx) {
  const int h  = blockIdx.x & 31;
  const int qt = blockIdx.x >> 5;
  const int hk = h >> 2;
  const int tid = threadIdx.x, lane = tid & 63, w = tid >> 6;
  const int l15 = lane & 15, lg = lane >> 4, fk = lg << 3;
  const int q0 = qt * 64 + w * 16;

  __shared__ __hip_bfloat16 Ps[4][16][64];  // per-wave P tile (wave-private slice)

  const __hip_bfloat16* Qh = Qb + (size_t)h  * TOK * HD;
  const __hip_bfloat16* Kh = Kb + (size_t)hk * TOK * HD;
  const __hip_bfloat16* Vh = Vt + (size_t)hk * HD * TOK;

  bf16x8 qf[2];
  qf[0] = *reinterpret_cast<const bf16x8*>(Qh + (size_t)(q0 + l15) * HD + fk);
  qf[1] = *reinterpret_cast<const bf16x8*>(Qh + (size_t)(q0 + l15) * HD + 32 + fk);

  float mst[4], lst[4];
  f32x4 oacc[4];
#pragma unroll
  for (int n = 0; n < 4; ++n) oacc[n] = (f32x4){0.f, 0.f, 0.f, 0.f};
#pragma unroll
  for (int r = 0; r < 4; ++r) { mst[r] = -1e30f; lst[r] = 0.f; }

  for (int kv0 = 0; kv0 <= q0 + 15; kv0 += 64) {
    // ---- S = Q K^T (16 q-rows x 64 kv-cols)
    f32x4 s[4];
#pragma unroll
    for (int n = 0; n < 4; ++n) {
      s[n] = (f32x4){0.f, 0.f, 0.f, 0.f};
#pragma unroll
      for (int kk = 0; kk < 2; ++kk) {
        bf16x8 kf = *reinterpret_cast<const bf16x8*>(
            Kh + (size_t)(kv0 + n * 16 + l15) * HD + kk * 32 + fk);
        s[n] = __builtin_amdgcn_mfma_f32_16x16x32_bf16(qf[kk], kf, s[n], 0, 0, 0);
      }
    }
    // ---- online softmax per q-row (row r of this lane's group lg)
    float p[4][4];  // [n][r]
#pragma unroll
    for (int r = 0; r < 4; ++r) {
      const int qrow = q0 + lg * 4 + r;
      float sv[4], rmax = -1e30f;
#pragma unroll
      for (int n = 0; n < 4; ++n) {
        const int col = kv0 + n * 16 + l15;
        float v = s[n][r] * 0.125f;           // 1/sqrt(64)
        v = (col <= qrow) ? v : -1e30f;       // causal mask
        sv[n] = v;
        rmax = fmaxf(rmax, v);
      }
#pragma unroll
      for (int off = 8; off >= 1; off >>= 1) rmax = fmaxf(rmax, __shfl_xor(rmax, off));
      const float mnew = fmaxf(mst[r], rmax);
      const float resc = __expf(mst[r] - mnew);
      float rsum = 0.f;
#pragma unroll
      for (int n = 0; n < 4; ++n) {
        float e = __expf(sv[n] - mnew);
        p[n][r] = e;
        rsum += e;
      }
#pragma unroll
      for (int off = 8; off >= 1; off >>= 1) rsum += __shfl_xor(rsum, off);
      lst[r] = lst[r] * resc + rsum;
      mst[r] = mnew;
#pragma unroll
      for (int n = 0; n < 4; ++n) oacc[n][r] *= resc;
    }
    // ---- P -> LDS (C-layout -> A-fragment relayout), wave-private, no block barrier
#pragma unroll
    for (int r = 0; r < 4; ++r)
#pragma unroll
      for (int n = 0; n < 4; ++n)
        Ps[w][lg * 4 + r][n * 16 + l15] = __float2bfloat16(p[n][r]);
    // ---- O += P V
#pragma unroll
    for (int kk = 0; kk < 2; ++kk) {
      bf16x8 pa = *reinterpret_cast<const bf16x8*>(&Ps[w][l15][kk * 32 + fk]);
#pragma unroll
      for (int n = 0; n < 4; ++n) {
        bf16x8 vf = *reinterpret_cast<const bf16x8*>(
            Vh + (size_t)(n * 16 + l15) * TOK + kv0 + kk * 32 + fk);
        oacc[n] = __builtin_amdgcn_mfma_f32_16x16x32_bf16(pa, vf, oacc[n], 0, 0, 0);
      }
    }
  }
  // ---- normalize + write ctx bf16 [t][EMB]
#pragma unroll
  for (int n = 0; n < 4; ++n)
#pragma unroll
    for (int r = 0; r < 4; ++r) {
      const int trow = q0 + lg * 4 + r;
      const float v = oacc[n][r] / lst[r];
      ctx[(size_t)trow * EMB + h * HD + n * 16 + l15] = __float2bfloat16(v);
    }
}

// ---------------------------------------------------------------- launch
extern "C" void kernel_launch(void* const* d_in, const int* in_sizes, int n_in,
                              void* d_out, int out_size, void* d_ws, size_t ws_size,
                              hipStream_t stream) {
  const float* x    = (const float*)d_in[0];
  const float* cosT = (const float*)d_in[1];
  const float* sinT = (const float*)d_in[2];
  const float* Wq   = (const float*)d_in[3];
  const float* Wk   = (const float*)d_in[4];
  const float* Wv   = (const float*)d_in[5];
  const float* Wo   = (const float*)d_in[6];
  float* out = (float*)d_out;

  const size_t M4 = (size_t)4 * 1024 * 1024;
  const size_t M1 = (size_t)1024 * 1024;

  char* ws = (char*)d_ws;
  __hip_bfloat16* xb   = (__hip_bfloat16*)ws;          // 8 MB
  __hip_bfloat16* Wc   = xb + M4;                      // 12 MB (3072x2048)
  __hip_bfloat16* Wob  = Wc + (size_t)6 * M1;          // 8 MB
  float*          qkv  = (float*)(Wob + M4);           // 24 MB (2048x3072)
  __hip_bfloat16* Qb   = (__hip_bfloat16*)(qkv + (size_t)TOK * QKVN);  // 8 MB
  __hip_bfloat16* Kb   = Qb + (size_t)NH * TOK * HD;   // 2 MB
  __hip_bfloat16* Vt   = Kb + (size_t)NKV * TOK * HD;  // 2 MB
  __hip_bfloat16* ctxb = Vt + (size_t)NKV * HD * TOK;  // 8 MB

  // 1. cast inputs/weights to bf16 (14M elements, 4/thread)
  cast_all<<<14336, 256, 0, stream>>>(x, Wq, Wk, Wv, Wo, xb, Wc, Wob);

  // 2. qkv = x @ Wqkv^T   (M=2048, N=3072, K=2048)
  gemm_bt<<<16 * 24, 256, 0, stream>>>(xb, Wc, qkv, TOK, QKVN, EMB);

  // 3. RoPE + bf16 cast + V transpose (3,670,016 threads)
  rope_cast<<<14336, 256, 0, stream>>>(qkv, cosT, sinT, Qb, Kb, Vt);

  // 4. causal GQA attention
  attn<<<32 * 32, 256, 0, stream>>>(Qb, Kb, Vt, ctxb);

  // 5. out = ctx @ Wo^T   (M=N=K=2048)
  gemm_bt<<<16 * 16, 256, 0, stream>>>(ctxb, Wob, out, TOK, EMB, EMB);
}

// Round 2
// 213.523 us; speedup vs baseline: 1.2749x; 1.2749x over previous
//
#include <hip/hip_runtime.h>
#include <hip/hip_bf16.h>
#include <stdint.h>

#define EMB   2048
#define TOK   2048
#define NH    32
#define NKV   8
#define HD    64
#define QKVN  3072   // 2048 q + 512 k + 512 v

typedef __attribute__((ext_vector_type(8))) short bf16x8;   // 8 bf16 = 4 VGPRs
typedef __attribute__((ext_vector_type(4))) float f32x4;
typedef __attribute__((ext_vector_type(16))) float f32x16;
typedef __attribute__((ext_vector_type(4))) unsigned int u32x4;

__device__ __forceinline__ void gld16(const void* g, void* l) {
  auto gp = reinterpret_cast<const int __attribute__((address_space(1)))*>(
      reinterpret_cast<uintptr_t>(g));
  auto lp = reinterpret_cast<int __attribute__((address_space(3)))*>(
      reinterpret_cast<uintptr_t>(l));
  __builtin_amdgcn_global_load_lds(gp, lp, 16, 0, 0);
}

__device__ __forceinline__ unsigned int cvtpk_bf16(float lo, float hi) {
  unsigned int r;
  asm("v_cvt_pk_bf16_f32 %0, %1, %2" : "=v"(r) : "v"(lo), "v"(hi));
  return r;
}
// v_permlane32_swap_b32 vdst, vsrc: after, vdst=[dst.lo|src.lo], vsrc=[dst.hi|src.hi]
__device__ __forceinline__ void pl32swap(unsigned int &a, unsigned int &b) {
  asm volatile("v_permlane32_swap_b32 %0, %1" : "+v"(a), "+v"(b));
}

// ---------------------------------------------------------------- cast fp32->bf16
__global__ void cast_all(const float* __restrict__ x,  const float* __restrict__ wq,
                         const float* __restrict__ wk, const float* __restrict__ wv,
                         const float* __restrict__ wo,
                         __hip_bfloat16* __restrict__ xb,
                         __hip_bfloat16* __restrict__ wc,
                         __hip_bfloat16* __restrict__ wob) {
  const size_t M4 = (size_t)4 * 1024 * 1024;
  const size_t M1 = (size_t)1024 * 1024;
  size_t i = ((size_t)blockIdx.x * 256 + threadIdx.x) * 4;
  const float* src;
  __hip_bfloat16* dst;
  if (i < M4)                    { src = x  + i;                 dst = xb  + i; }
  else if (i < 2*M4)             { src = wq + (i - M4);          dst = wc  + (i - M4); }
  else if (i < 2*M4 + M1)        { src = wk + (i - 2*M4);        dst = wc  + M4 + (i - 2*M4); }
  else if (i < 2*M4 + 2*M1)      { src = wv + (i - 2*M4 - M1);   dst = wc  + M4 + M1 + (i - 2*M4 - M1); }
  else                           { src = wo + (i - 2*M4 - 2*M1); dst = wob + (i - 2*M4 - 2*M1); }
  float4 v = *reinterpret_cast<const float4*>(src);
  dst[0] = __float2bfloat16(v.x);
  dst[1] = __float2bfloat16(v.y);
  dst[2] = __float2bfloat16(v.z);
  dst[3] = __float2bfloat16(v.w);
}

// ---------------------------------------------------------------- GEMM  C = A * B^T
__global__ __launch_bounds__(256) void gemm_bt(const __hip_bfloat16* __restrict__ A,
                                               const __hip_bfloat16* __restrict__ B,
                                               float* __restrict__ C,
                                               int M, int N, int K) {
  __shared__ __hip_bfloat16 As[128 * 64];
  __shared__ __hip_bfloat16 Bs[128 * 64];
  const int nbc = N >> 7;
  const int br  = blockIdx.x / nbc;
  const int bc  = blockIdx.x % nbc;
  const int tid  = threadIdx.x;
  const int lane = tid & 63;
  const int w    = tid >> 6;
  const int wr   = w >> 1, wc = w & 1;
  const int l15  = lane & 15;
  const int fk   = (lane >> 4) << 3;

  f32x4 acc[4][4];
#pragma unroll
  for (int m = 0; m < 4; ++m)
#pragma unroll
    for (int n = 0; n < 4; ++n) acc[m][n] = (f32x4){0.f, 0.f, 0.f, 0.f};

  const __hip_bfloat16* Ag = A + (size_t)br * 128 * K;
  const __hip_bfloat16* Bg = B + (size_t)bc * 128 * K;

  int srow[4], scol[4];
#pragma unroll
  for (int r = 0; r < 4; ++r) {
    int o = (w * 4 + r) * 1024 + lane * 16;
    srow[r] = o >> 7;
    scol[r] = (o & 127) >> 1;
  }

  for (int kt = 0; kt < K; kt += 64) {
#pragma unroll
    for (int r = 0; r < 4; ++r) {
      const int c = w * 4 + r;
      gld16(Ag + (size_t)srow[r] * K + kt + scol[r], (char*)As + c * 1024);
      gld16(Bg + (size_t)srow[r] * K + kt + scol[r], (char*)Bs + c * 1024);
    }
    __syncthreads();

    bf16x8 a[4][2], b[4][2];
#pragma unroll
    for (int m = 0; m < 4; ++m)
#pragma unroll
      for (int kk = 0; kk < 2; ++kk)
        a[m][kk] = *reinterpret_cast<const bf16x8*>(
            (const char*)As + ((wr * 64 + m * 16 + l15) * 64 + kk * 32 + fk) * 2);
#pragma unroll
    for (int n = 0; n < 4; ++n)
#pragma unroll
      for (int kk = 0; kk < 2; ++kk)
        b[n][kk] = *reinterpret_cast<const bf16x8*>(
            (const char*)Bs + ((wc * 64 + n * 16 + l15) * 64 + kk * 32 + fk) * 2);

#pragma unroll
    for (int m = 0; m < 4; ++m)
#pragma unroll
      for (int n = 0; n < 4; ++n)
#pragma unroll
        for (int kk = 0; kk < 2; ++kk)
          acc[m][n] = __builtin_amdgcn_mfma_f32_16x16x32_bf16(a[m][kk], b[n][kk],
                                                              acc[m][n], 0, 0, 0);
    __syncthreads();
  }

  const int row0 = br * 128 + wr * 64;
  const int col0 = bc * 128 + wc * 64;
  const int rb   = (lane >> 4) * 4;
#pragma unroll
  for (int m = 0; m < 4; ++m)
#pragma unroll
    for (int n = 0; n < 4; ++n)
#pragma unroll
      for (int r = 0; r < 4; ++r)
        C[(size_t)(row0 + m * 16 + rb + r) * N + col0 + n * 16 + l15] = acc[m][n][r];
}

// ---------------------------------------------------------------- RoPE + cast + V transpose
// Q gets 1/sqrt(HD)=0.125 folded in. Vt is [NKV][HD][TOK].
__global__ void rope_cast(const float* __restrict__ qkv,
                          const float* __restrict__ cosT, const float* __restrict__ sinT,
                          __hip_bfloat16* __restrict__ Qb,
                          __hip_bfloat16* __restrict__ Kb,
                          __hip_bfloat16* __restrict__ Vt) {
  const int QP = TOK * NH * (HD / 2);   // 2,097,152
  const int KP = TOK * NKV * (HD / 2);  //   524,288
  int idx = blockIdx.x * 256 + threadIdx.x;
  if (idx < QP) {
    int d = idx & 31, h = (idx >> 5) & 31, t = idx >> 10;
    const float* row = qkv + (size_t)t * QKVN + h * 64;
    float x1 = row[d], x2 = row[d + 32];
    float o1 = (x1 * cosT[t * 64 + d]      - x2 * sinT[t * 64 + d])      * 0.125f;
    float o2 = (x2 * cosT[t * 64 + d + 32] + x1 * sinT[t * 64 + d + 32]) * 0.125f;
    __hip_bfloat16* q = Qb + ((size_t)h * TOK + t) * HD;
    q[d]      = __float2bfloat16(o1);
    q[d + 32] = __float2bfloat16(o2);
  } else if (idx < QP + KP) {
    int j = idx - QP;
    int d = j & 31, h = (j >> 5) & 7, t = j >> 8;
    const float* row = qkv + (size_t)t * QKVN + 2048 + h * 64;
    float x1 = row[d], x2 = row[d + 32];
    float o1 = x1 * cosT[t * 64 + d]      - x2 * sinT[t * 64 + d];
    float o2 = x2 * cosT[t * 64 + d + 32] + x1 * sinT[t * 64 + d + 32];
    __hip_bfloat16* k = Kb + ((size_t)h * TOK + t) * HD;
    k[d]      = __float2bfloat16(o1);
    k[d + 32] = __float2bfloat16(o2);
  } else {
    int j = idx - QP - KP;
    int t = j & (TOK - 1), d = (j >> 11) & 63, hk = j >> 17;
    float v = qkv[(size_t)t * QKVN + 2560 + hk * 64 + d];
    Vt[(size_t)j] = __float2bfloat16(v);
  }
}

// ---------------------------------------------------------------- causal GQA flash attention
// 32x32 MFMA, swapped QK^T (S^T), O^T accumulation; lane owns one q-column.
// grid = 16 qtiles (desc) * 32 heads; block = 256 (4 waves, each 32 q-rows).
__global__ __launch_bounds__(256) void attn2(const __hip_bfloat16* __restrict__ Qb,
                                             const __hip_bfloat16* __restrict__ Kb,
                                             const __hip_bfloat16* __restrict__ Vt,
                                             __hip_bfloat16* __restrict__ ctx) {
  const int h  = blockIdx.x & 31;
  const int qt = 15 - (blockIdx.x >> 5);          // longest blocks dispatch first
  const int hk = h >> 2;
  const int lane = threadIdx.x & 63, w = threadIdx.x >> 6;
  const int l31 = lane & 31, hi = lane >> 5;
  const int q0 = qt * 128 + w * 32;

  __shared__ float T[4][64][33];                  // epilogue transpose, padded (+1)

  const __hip_bfloat16* Qh = Qb + (size_t)h  * TOK * HD;
  const __hip_bfloat16* Kh = Kb + (size_t)hk * TOK * HD;
  const __hip_bfloat16* Vh = Vt + (size_t)hk * HD * TOK;

  // Q B-frag (lane holds Q[q0+l31][d = ks*16 + hi*8 + 0..7]), hoisted
  bf16x8 qf[4];
#pragma unroll
  for (int ks = 0; ks < 4; ++ks)
    qf[ks] = *reinterpret_cast<const bf16x8*>(
        Qh + (size_t)(q0 + l31) * HD + ks * 16 + hi * 8);

  f32x16 oa0, oa1;                                // O^T acc: d rows 0..31 / 32..63
#pragma unroll
  for (int r = 0; r < 16; ++r) { oa0[r] = 0.f; oa1[r] = 0.f; }
  float m = -1e30f, l = 0.f;

  for (int kv0 = 0; kv0 <= q0; kv0 += 32) {
    // ---- S^T (32 kv x 32 q) = K * Q^T over D=64
    f32x16 st;
#pragma unroll
    for (int r = 0; r < 16; ++r) st[r] = 0.f;
#pragma unroll
    for (int ks = 0; ks < 4; ++ks) {
      bf16x8 kf = *reinterpret_cast<const bf16x8*>(
          Kh + (size_t)(kv0 + l31) * HD + ks * 16 + hi * 8);
      st = __builtin_amdgcn_mfma_f32_32x32x16_bf16(kf, qf[ks], st, 0, 0, 0);
    }
    float s[16];
#pragma unroll
    for (int r = 0; r < 16; ++r) s[r] = st[r];
    if (kv0 == q0) {                              // diagonal tile: causal mask
#pragma unroll
      for (int r = 0; r < 16; ++r) {
        const int crow = (r & 3) + 8 * (r >> 2) + 4 * hi;   // kv offset in tile
        s[r] = (crow <= l31) ? s[r] : -1e30f;
      }
    }
    // ---- row max: 15-op tree + 1 cross-half shuffle (lane-local q column)
    float t0 = fmaxf(fmaxf(s[0], s[1]),  fmaxf(s[2], s[3]));
    float t1 = fmaxf(fmaxf(s[4], s[5]),  fmaxf(s[6], s[7]));
    float t2 = fmaxf(fmaxf(s[8], s[9]),  fmaxf(s[10], s[11]));
    float t3 = fmaxf(fmaxf(s[12], s[13]), fmaxf(s[14], s[15]));
    float rmax = fmaxf(fmaxf(t0, t1), fmaxf(t2, t3));
    rmax = fmaxf(rmax, __shfl_xor(rmax, 32));
    const float mnew = fmaxf(m, rmax);
    const float resc = __expf(m - mnew);
    float p[16];
#pragma unroll
    for (int r = 0; r < 16; ++r) p[r] = __expf(s[r] - mnew);
    float u0 = (p[0] + p[1]) + (p[2] + p[3]);
    float u1 = (p[4] + p[5]) + (p[6] + p[7]);
    float u2 = (p[8] + p[9]) + (p[10] + p[11]);
    float u3 = (p[12] + p[13]) + (p[14] + p[15]);
    float rsum = (u0 + u1) + (u2 + u3);
    rsum += __shfl_xor(rsum, 32);
    l = l * resc + rsum;
    m = mnew;
#pragma unroll
    for (int r = 0; r < 16; ++r) { oa0[r] *= resc; oa1[r] *= resc; }

    // ---- P -> bf16 B-frags fully in-register: 8 cvt_pk + 4 permlane32_swap
    unsigned int wpk[8];
#pragma unroll
    for (int j = 0; j < 8; ++j) wpk[j] = cvtpk_bf16(p[2 * j], p[2 * j + 1]);

#pragma unroll
    for (int ks2 = 0; ks2 < 2; ++ks2) {
      unsigned int a0 = wpk[4 * ks2 + 0], b0 = wpk[4 * ks2 + 2];
      pl32swap(a0, b0);   // a0 = kv +0,1 ; b0 = kv +4,5
      unsigned int a1 = wpk[4 * ks2 + 1], b1 = wpk[4 * ks2 + 3];
      pl32swap(a1, b1);   // a1 = kv +2,3 ; b1 = kv +6,7
      u32x4 pw; pw[0] = a0; pw[1] = a1; pw[2] = b0; pw[3] = b1;
      bf16x8 pf = *reinterpret_cast<bf16x8*>(&pw);
      // ---- O^T += V^T * P^T (A = V^T rows d, kv-contig from Vt)
      bf16x8 vf0 = *reinterpret_cast<const bf16x8*>(
          Vh + (size_t)l31 * TOK + kv0 + ks2 * 16 + hi * 8);
      bf16x8 vf1 = *reinterpret_cast<const bf16x8*>(
          Vh + (size_t)(32 + l31) * TOK + kv0 + ks2 * 16 + hi * 8);
      oa0 = __builtin_amdgcn_mfma_f32_32x32x16_bf16(vf0, pf, oa0, 0, 0, 0);
      oa1 = __builtin_amdgcn_mfma_f32_32x32x16_bf16(vf1, pf, oa1, 0, 0, 0);
    }
  }

  // ---- epilogue: normalize (lane-local l), LDS untranspose, coalesced ctx write
  const float inv = 1.f / l;
#pragma unroll
  for (int r = 0; r < 16; ++r) {
    const int d = (r & 3) + 8 * (r >> 2) + 4 * hi;
    T[w][d][l31]      = oa0[r] * inv;
    T[w][d + 32][l31] = oa1[r] * inv;
  }
  // wave-private tile: no barrier needed
#pragma unroll 4
  for (int i = 0; i < 32; ++i) {
    const float v = T[w][lane][i];
    ctx[(size_t)(q0 + i) * EMB + h * HD + lane] = __float2bfloat16(v);
  }
}

// ---------------------------------------------------------------- launch
extern "C" void kernel_launch(void* const* d_in, const int* in_sizes, int n_in,
                              void* d_out, int out_size, void* d_ws, size_t ws_size,
                              hipStream_t stream) {
  const float* x    = (const float*)d_in[0];
  const float* cosT = (const float*)d_in[1];
  const float* sinT = (const float*)d_in[2];
  const float* Wq   = (const float*)d_in[3];
  const float* Wk   = (const float*)d_in[4];
  const float* Wv   = (const float*)d_in[5];
  const float* Wo   = (const float*)d_in[6];
  float* out = (float*)d_out;

  const size_t M4 = (size_t)4 * 1024 * 1024;
  const size_t M1 = (size_t)1024 * 1024;

  char* ws = (char*)d_ws;
  __hip_bfloat16* xb   = (__hip_bfloat16*)ws;
  __hip_bfloat16* Wc   = xb + M4;
  __hip_bfloat16* Wob  = Wc + (size_t)6 * M1;
  float*          qkv  = (float*)(Wob + M4);
  __hip_bfloat16* Qb   = (__hip_bfloat16*)(qkv + (size_t)TOK * QKVN);
  __hip_bfloat16* Kb   = Qb + (size_t)NH * TOK * HD;
  __hip_bfloat16* Vt   = Kb + (size_t)NKV * TOK * HD;
  __hip_bfloat16* ctxb = Vt + (size_t)NKV * HD * TOK;

  cast_all<<<14336, 256, 0, stream>>>(x, Wq, Wk, Wv, Wo, xb, Wc, Wob);

  // qkv = x @ Wqkv^T   (M=2048, N=3072, K=2048)
  gemm_bt<<<16 * 24, 256, 0, stream>>>(xb, Wc, qkv, TOK, QKVN, EMB);

  rope_cast<<<14336, 256, 0, stream>>>(qkv, cosT, sinT, Qb, Kb, Vt);

  // causal GQA attention (swapped-operand 32x32, qt descending)
  attn2<<<16 * 32, 256, 0, stream>>>(Qb, Kb, Vt, ctxb);

  // out = ctx @ Wo^T   (M=N=K=2048)
  gemm_bt<<<16 * 16, 256, 0, stream>>>(ctxb, Wob, out, TOK, EMB, EMB);
}

// Round 3
// 198.231 us; speedup vs baseline: 1.3733x; 1.0771x over previous
//
#include <hip/hip_runtime.h>
#include <hip/hip_bf16.h>
#include <stdint.h>

#define EMB   2048
#define TOK   2048
#define NH    32
#define NKV   8
#define HD    64
#define QKVN  3072   // 2048 q + 512 k + 512 v

typedef __attribute__((ext_vector_type(8))) short bf16x8;   // 8 bf16 = 4 VGPRs
typedef __attribute__((ext_vector_type(4))) float f32x4;
typedef __attribute__((ext_vector_type(16))) float f32x16;
typedef __attribute__((ext_vector_type(4))) unsigned int u32x4;

__device__ __forceinline__ void gld16(const void* g, void* l) {
  auto gp = reinterpret_cast<const int __attribute__((address_space(1)))*>(
      reinterpret_cast<uintptr_t>(g));
  auto lp = reinterpret_cast<int __attribute__((address_space(3)))*>(
      reinterpret_cast<uintptr_t>(l));
  __builtin_amdgcn_global_load_lds(gp, lp, 16, 0, 0);
}

__device__ __forceinline__ unsigned int cvtpk_bf16(float lo, float hi) {
  unsigned int r;
  asm("v_cvt_pk_bf16_f32 %0, %1, %2" : "=v"(r) : "v"(lo), "v"(hi));
  return r;
}
// v_permlane32_swap_b32 vdst, vsrc: after, vdst=[dst.lo|src.lo], vsrc=[dst.hi|src.hi]
__device__ __forceinline__ void pl32swap(unsigned int &a, unsigned int &b) {
  asm volatile("v_permlane32_swap_b32 %0, %1" : "+v"(a), "+v"(b));
}
__device__ __forceinline__ float fexp2(float x) {  // v_exp_f32 IS 2^x
  float r;
  asm("v_exp_f32 %0, %1" : "=v"(r) : "v"(x));
  return r;
}

// ---------------------------------------------------------------- cast fp32->bf16
__global__ void cast_all(const float* __restrict__ x,  const float* __restrict__ wq,
                         const float* __restrict__ wk, const float* __restrict__ wv,
                         const float* __restrict__ wo,
                         __hip_bfloat16* __restrict__ xb,
                         __hip_bfloat16* __restrict__ wc,
                         __hip_bfloat16* __restrict__ wob) {
  const size_t M4 = (size_t)4 * 1024 * 1024;
  const size_t M1 = (size_t)1024 * 1024;
  size_t i = ((size_t)blockIdx.x * 256 + threadIdx.x) * 4;
  const float* src;
  __hip_bfloat16* dst;
  if (i < M4)                    { src = x  + i;                 dst = xb  + i; }
  else if (i < 2*M4)             { src = wq + (i - M4);          dst = wc  + (i - M4); }
  else if (i < 2*M4 + M1)        { src = wk + (i - 2*M4);        dst = wc  + M4 + (i - 2*M4); }
  else if (i < 2*M4 + 2*M1)      { src = wv + (i - 2*M4 - M1);   dst = wc  + M4 + M1 + (i - 2*M4 - M1); }
  else                           { src = wo + (i - 2*M4 - 2*M1); dst = wob + (i - 2*M4 - 2*M1); }
  float4 v = *reinterpret_cast<const float4*>(src);
  dst[0] = __float2bfloat16(v.x);
  dst[1] = __float2bfloat16(v.y);
  dst[2] = __float2bfloat16(v.z);
  dst[3] = __float2bfloat16(v.w);
}

// ---------------------------------------------------------------- GEMM  C = A * B^T
__global__ __launch_bounds__(256) void gemm_bt(const __hip_bfloat16* __restrict__ A,
                                               const __hip_bfloat16* __restrict__ B,
                                               float* __restrict__ C,
                                               int M, int N, int K) {
  __shared__ __hip_bfloat16 As[128 * 64];
  __shared__ __hip_bfloat16 Bs[128 * 64];
  const int nbc = N >> 7;
  const int br  = blockIdx.x / nbc;
  const int bc  = blockIdx.x % nbc;
  const int tid  = threadIdx.x;
  const int lane = tid & 63;
  const int w    = tid >> 6;
  const int wr   = w >> 1, wc = w & 1;
  const int l15  = lane & 15;
  const int fk   = (lane >> 4) << 3;

  f32x4 acc[4][4];
#pragma unroll
  for (int m = 0; m < 4; ++m)
#pragma unroll
    for (int n = 0; n < 4; ++n) acc[m][n] = (f32x4){0.f, 0.f, 0.f, 0.f};

  const __hip_bfloat16* Ag = A + (size_t)br * 128 * K;
  const __hip_bfloat16* Bg = B + (size_t)bc * 128 * K;

  int srow[4], scol[4];
#pragma unroll
  for (int r = 0; r < 4; ++r) {
    int o = (w * 4 + r) * 1024 + lane * 16;
    srow[r] = o >> 7;
    scol[r] = (o & 127) >> 1;
  }

  for (int kt = 0; kt < K; kt += 64) {
#pragma unroll
    for (int r = 0; r < 4; ++r) {
      const int c = w * 4 + r;
      gld16(Ag + (size_t)srow[r] * K + kt + scol[r], (char*)As + c * 1024);
      gld16(Bg + (size_t)srow[r] * K + kt + scol[r], (char*)Bs + c * 1024);
    }
    __syncthreads();

    bf16x8 a[4][2], b[4][2];
#pragma unroll
    for (int m = 0; m < 4; ++m)
#pragma unroll
      for (int kk = 0; kk < 2; ++kk)
        a[m][kk] = *reinterpret_cast<const bf16x8*>(
            (const char*)As + ((wr * 64 + m * 16 + l15) * 64 + kk * 32 + fk) * 2);
#pragma unroll
    for (int n = 0; n < 4; ++n)
#pragma unroll
      for (int kk = 0; kk < 2; ++kk)
        b[n][kk] = *reinterpret_cast<const bf16x8*>(
            (const char*)Bs + ((wc * 64 + n * 16 + l15) * 64 + kk * 32 + fk) * 2);

#pragma unroll
    for (int m = 0; m < 4; ++m)
#pragma unroll
      for (int n = 0; n < 4; ++n)
#pragma unroll
        for (int kk = 0; kk < 2; ++kk)
          acc[m][n] = __builtin_amdgcn_mfma_f32_16x16x32_bf16(a[m][kk], b[n][kk],
                                                              acc[m][n], 0, 0, 0);
    __syncthreads();
  }

  const int row0 = br * 128 + wr * 64;
  const int col0 = bc * 128 + wc * 64;
  const int rb   = (lane >> 4) * 4;
#pragma unroll
  for (int m = 0; m < 4; ++m)
#pragma unroll
    for (int n = 0; n < 4; ++n)
#pragma unroll
      for (int r = 0; r < 4; ++r)
        C[(size_t)(row0 + m * 16 + rb + r) * N + col0 + n * 16 + l15] = acc[m][n][r];
}

// ---------------------------------------------------------------- RoPE + cast + V transpose
// Q gets 1/sqrt(HD) * log2(e) folded in (attention uses exp2-domain softmax).
// Vt is [NKV][HD][TOK].
#define QSCALE 0.1803368801111243f   // 0.125 * log2(e)
__global__ void rope_cast(const float* __restrict__ qkv,
                          const float* __restrict__ cosT, const float* __restrict__ sinT,
                          __hip_bfloat16* __restrict__ Qb,
                          __hip_bfloat16* __restrict__ Kb,
                          __hip_bfloat16* __restrict__ Vt) {
  const int QP = TOK * NH * (HD / 2);   // 2,097,152
  const int KP = TOK * NKV * (HD / 2);  //   524,288
  int idx = blockIdx.x * 256 + threadIdx.x;
  if (idx < QP) {
    int d = idx & 31, h = (idx >> 5) & 31, t = idx >> 10;
    const float* row = qkv + (size_t)t * QKVN + h * 64;
    float x1 = row[d], x2 = row[d + 32];
    float o1 = (x1 * cosT[t * 64 + d]      - x2 * sinT[t * 64 + d])      * QSCALE;
    float o2 = (x2 * cosT[t * 64 + d + 32] + x1 * sinT[t * 64 + d + 32]) * QSCALE;
    __hip_bfloat16* q = Qb + ((size_t)h * TOK + t) * HD;
    q[d]      = __float2bfloat16(o1);
    q[d + 32] = __float2bfloat16(o2);
  } else if (idx < QP + KP) {
    int j = idx - QP;
    int d = j & 31, h = (j >> 5) & 7, t = j >> 8;
    const float* row = qkv + (size_t)t * QKVN + 2048 + h * 64;
    float x1 = row[d], x2 = row[d + 32];
    float o1 = x1 * cosT[t * 64 + d]      - x2 * sinT[t * 64 + d];
    float o2 = x2 * cosT[t * 64 + d + 32] + x1 * sinT[t * 64 + d + 32];
    __hip_bfloat16* k = Kb + ((size_t)h * TOK + t) * HD;
    k[d]      = __float2bfloat16(o1);
    k[d + 32] = __float2bfloat16(o2);
  } else {
    int j = idx - QP - KP;
    int t = j & (TOK - 1), d = (j >> 11) & 63, hk = j >> 17;
    float v = qkv[(size_t)t * QKVN + 2560 + hk * 64 + d];
    Vt[(size_t)j] = __float2bfloat16(v);
  }
}

// ---------------------------------------------------------------- causal GQA flash attention
// 1 wave per block; swapped QK^T (S^T) + O^T accumulation; register-double-buffered
// K/V prefetch; exp2-domain online softmax.
struct KVb { bf16x8 k0, k1, k2, k3, v00, v01, v10, v11; };

__device__ __forceinline__ void load_kv(KVb& b, const __hip_bfloat16* Kh,
                                        const __hip_bfloat16* Vh, int base,
                                        int l31, int hi) {
  const __hip_bfloat16* Kp = Kh + (size_t)(base + l31) * HD + hi * 8;
  b.k0 = *reinterpret_cast<const bf16x8*>(Kp);
  b.k1 = *reinterpret_cast<const bf16x8*>(Kp + 16);
  b.k2 = *reinterpret_cast<const bf16x8*>(Kp + 32);
  b.k3 = *reinterpret_cast<const bf16x8*>(Kp + 48);
  const __hip_bfloat16* Vp = Vh + (size_t)l31 * TOK + base + hi * 8;
  b.v00 = *reinterpret_cast<const bf16x8*>(Vp);
  b.v01 = *reinterpret_cast<const bf16x8*>(Vp + 16);
  b.v10 = *reinterpret_cast<const bf16x8*>(Vp + (size_t)32 * TOK);
  b.v11 = *reinterpret_cast<const bf16x8*>(Vp + (size_t)32 * TOK + 16);
}

__device__ __forceinline__ void compute_tile(const KVb& b, bool diag,
                                             const bf16x8 (&qf)[4],
                                             int l31, int hi,
                                             float& m, float& l,
                                             f32x16& oa0, f32x16& oa1) {
  f32x16 st;
#pragma unroll
  for (int r = 0; r < 16; ++r) st[r] = 0.f;
  st = __builtin_amdgcn_mfma_f32_32x32x16_bf16(b.k0, qf[0], st, 0, 0, 0);
  st = __builtin_amdgcn_mfma_f32_32x32x16_bf16(b.k1, qf[1], st, 0, 0, 0);
  st = __builtin_amdgcn_mfma_f32_32x32x16_bf16(b.k2, qf[2], st, 0, 0, 0);
  st = __builtin_amdgcn_mfma_f32_32x32x16_bf16(b.k3, qf[3], st, 0, 0, 0);

  float s[16];
#pragma unroll
  for (int r = 0; r < 16; ++r) s[r] = st[r];
  if (diag) {
#pragma unroll
    for (int r = 0; r < 16; ++r) {
      const int crow = (r & 3) + 8 * (r >> 2) + 4 * hi;   // kv offset in tile
      s[r] = (crow <= l31) ? s[r] : -1e30f;
    }
  }
  float t0 = fmaxf(fmaxf(s[0], s[1]),   fmaxf(s[2], s[3]));
  float t1 = fmaxf(fmaxf(s[4], s[5]),   fmaxf(s[6], s[7]));
  float t2 = fmaxf(fmaxf(s[8], s[9]),   fmaxf(s[10], s[11]));
  float t3 = fmaxf(fmaxf(s[12], s[13]), fmaxf(s[14], s[15]));
  float rmax = fmaxf(fmaxf(t0, t1), fmaxf(t2, t3));
  rmax = fmaxf(rmax, __shfl_xor(rmax, 32));
  const float mnew = fmaxf(m, rmax);
  const float resc = fexp2(m - mnew);      // exp2 domain (log2e folded into Q)
  float p[16];
#pragma unroll
  for (int r = 0; r < 16; ++r) p[r] = fexp2(s[r] - mnew);
  float u0 = (p[0] + p[1]) + (p[2] + p[3]);
  float u1 = (p[4] + p[5]) + (p[6] + p[7]);
  float u2 = (p[8] + p[9]) + (p[10] + p[11]);
  float u3 = (p[12] + p[13]) + (p[14] + p[15]);
  float rsum = (u0 + u1) + (u2 + u3);
  rsum += __shfl_xor(rsum, 32);
  l = l * resc + rsum;
  m = mnew;
#pragma unroll
  for (int r = 0; r < 16; ++r) { oa0[r] *= resc; oa1[r] *= resc; }

  // P -> bf16 B-frags in-register: 8 cvt_pk + 4 permlane32_swap
  unsigned int wpk[8];
#pragma unroll
  for (int j = 0; j < 8; ++j) wpk[j] = cvtpk_bf16(p[2 * j], p[2 * j + 1]);

  {
    unsigned int a0 = wpk[0], b0 = wpk[2];  pl32swap(a0, b0);
    unsigned int a1 = wpk[1], b1 = wpk[3];  pl32swap(a1, b1);
    u32x4 pw; pw[0] = a0; pw[1] = a1; pw[2] = b0; pw[3] = b1;
    bf16x8 pf = *reinterpret_cast<bf16x8*>(&pw);
    oa0 = __builtin_amdgcn_mfma_f32_32x32x16_bf16(b.v00, pf, oa0, 0, 0, 0);
    oa1 = __builtin_amdgcn_mfma_f32_32x32x16_bf16(b.v10, pf, oa1, 0, 0, 0);
  }
  {
    unsigned int a0 = wpk[4], b0 = wpk[6];  pl32swap(a0, b0);
    unsigned int a1 = wpk[5], b1 = wpk[7];  pl32swap(a1, b1);
    u32x4 pw; pw[0] = a0; pw[1] = a1; pw[2] = b0; pw[3] = b1;
    bf16x8 pf = *reinterpret_cast<bf16x8*>(&pw);
    oa0 = __builtin_amdgcn_mfma_f32_32x32x16_bf16(b.v01, pf, oa0, 0, 0, 0);
    oa1 = __builtin_amdgcn_mfma_f32_32x32x16_bf16(b.v11, pf, oa1, 0, 0, 0);
  }
}

// grid = 64 strips (desc) * 32 heads; block = 64 threads (1 wave, 32 q-rows)
__global__ __launch_bounds__(64) void attn3(const __hip_bfloat16* __restrict__ Qb,
                                            const __hip_bfloat16* __restrict__ Kb,
                                            const __hip_bfloat16* __restrict__ Vt,
                                            __hip_bfloat16* __restrict__ ctx) {
  const int h     = blockIdx.x & 31;
  const int strip = 63 - (blockIdx.x >> 5);       // longest blocks dispatch first
  const int hk    = h >> 2;
  const int lane  = threadIdx.x & 63;
  const int l31   = lane & 31, hi = lane >> 5;
  const int q0    = strip * 32;

  __shared__ float T[64][33];                     // epilogue transpose, padded

  const __hip_bfloat16* Qh = Qb + (size_t)h  * TOK * HD;
  const __hip_bfloat16* Kh = Kb + (size_t)hk * TOK * HD;
  const __hip_bfloat16* Vh = Vt + (size_t)hk * HD * TOK;

  bf16x8 qf[4];
#pragma unroll
  for (int ks = 0; ks < 4; ++ks)
    qf[ks] = *reinterpret_cast<const bf16x8*>(
        Qh + (size_t)(q0 + l31) * HD + ks * 16 + hi * 8);

  f32x16 oa0, oa1;
#pragma unroll
  for (int r = 0; r < 16; ++r) { oa0[r] = 0.f; oa1[r] = 0.f; }
  float m = -1e30f, l = 0.f;

  KVb A, B;
  load_kv(A, Kh, Vh, 0, l31, hi);
  int kv = 0;
  for (;;) {
    int nxt = kv + 32;
    if (nxt <= q0) load_kv(B, Kh, Vh, nxt, l31, hi);   // prefetch next tile
    compute_tile(A, kv == q0, qf, l31, hi, m, l, oa0, oa1);
    kv = nxt;
    if (kv > q0) break;
    nxt = kv + 32;
    if (nxt <= q0) load_kv(A, Kh, Vh, nxt, l31, hi);
    compute_tile(B, kv == q0, qf, l31, hi, m, l, oa0, oa1);
    kv = nxt;
    if (kv > q0) break;
  }

  // epilogue: normalize, LDS untranspose, coalesced ctx write
  const float inv = 1.f / l;
#pragma unroll
  for (int r = 0; r < 16; ++r) {
    const int d = (r & 3) + 8 * (r >> 2) + 4 * hi;
    T[d][l31]      = oa0[r] * inv;
    T[d + 32][l31] = oa1[r] * inv;
  }
#pragma unroll 4
  for (int i = 0; i < 32; ++i) {
    const float v = T[lane][i];
    ctx[(size_t)(q0 + i) * EMB + h * HD + lane] = __float2bfloat16(v);
  }
}

// ---------------------------------------------------------------- launch
extern "C" void kernel_launch(void* const* d_in, const int* in_sizes, int n_in,
                              void* d_out, int out_size, void* d_ws, size_t ws_size,
                              hipStream_t stream) {
  const float* x    = (const float*)d_in[0];
  const float* cosT = (const float*)d_in[1];
  const float* sinT = (const float*)d_in[2];
  const float* Wq   = (const float*)d_in[3];
  const float* Wk   = (const float*)d_in[4];
  const float* Wv   = (const float*)d_in[5];
  const float* Wo   = (const float*)d_in[6];
  float* out = (float*)d_out;

  const size_t M4 = (size_t)4 * 1024 * 1024;
  const size_t M1 = (size_t)1024 * 1024;

  char* ws = (char*)d_ws;
  __hip_bfloat16* xb   = (__hip_bfloat16*)ws;
  __hip_bfloat16* Wc   = xb + M4;
  __hip_bfloat16* Wob  = Wc + (size_t)6 * M1;
  float*          qkv  = (float*)(Wob + M4);
  __hip_bfloat16* Qb   = (__hip_bfloat16*)(qkv + (size_t)TOK * QKVN);
  __hip_bfloat16* Kb   = Qb + (size_t)NH * TOK * HD;
  __hip_bfloat16* Vt   = Kb + (size_t)NKV * TOK * HD;
  __hip_bfloat16* ctxb = Vt + (size_t)NKV * HD * TOK;

  cast_all<<<14336, 256, 0, stream>>>(x, Wq, Wk, Wv, Wo, xb, Wc, Wob);

  // qkv = x @ Wqkv^T   (M=2048, N=3072, K=2048)
  gemm_bt<<<16 * 24, 256, 0, stream>>>(xb, Wc, qkv, TOK, QKVN, EMB);

  rope_cast<<<14336, 256, 0, stream>>>(qkv, cosT, sinT, Qb, Kb, Vt);

  // causal GQA attention: 1-wave blocks, strip-descending
  attn3<<<64 * 32, 64, 0, stream>>>(Qb, Kb, Vt, ctxb);

  // out = ctx @ Wo^T   (M=N=K=2048)
  gemm_bt<<<16 * 16, 256, 0, stream>>>(ctxb, Wob, out, TOK, EMB, EMB);
}

// Round 4
// 175.549 us; speedup vs baseline: 1.5507x; 1.1292x over previous
//
#include <hip/hip_runtime.h>
#include <hip/hip_bf16.h>
#include <stdint.h>

#define EMB   2048
#define TOK   2048
#define NH    32
#define NKV   8
#define HD    64
#define QKVN  3072   // 2048 q + 512 k + 512 v

typedef __attribute__((ext_vector_type(8))) short bf16x8;   // 8 bf16 = 4 VGPRs
typedef __attribute__((ext_vector_type(4))) float f32x4;
typedef __attribute__((ext_vector_type(16))) float f32x16;
typedef __attribute__((ext_vector_type(4))) unsigned int u32x4;

__device__ __forceinline__ void gld16(const void* g, void* l) {
  auto gp = reinterpret_cast<const int __attribute__((address_space(1)))*>(
      reinterpret_cast<uintptr_t>(g));
  auto lp = reinterpret_cast<int __attribute__((address_space(3)))*>(
      reinterpret_cast<uintptr_t>(l));
  __builtin_amdgcn_global_load_lds(gp, lp, 16, 0, 0);
}

__device__ __forceinline__ unsigned int cvtpk_bf16(float lo, float hi) {
  unsigned int r;
  asm("v_cvt_pk_bf16_f32 %0, %1, %2" : "=v"(r) : "v"(lo), "v"(hi));
  return r;
}
// v_permlane32_swap_b32 vdst, vsrc: after, vdst=[dst.lo|src.lo], vsrc=[dst.hi|src.hi]
__device__ __forceinline__ void pl32swap(unsigned int &a, unsigned int &b) {
  asm volatile("v_permlane32_swap_b32 %0, %1" : "+v"(a), "+v"(b));
}
__device__ __forceinline__ float fexp2(float x) {  // v_exp_f32 IS 2^x
  float r;
  asm("v_exp_f32 %0, %1" : "=v"(r) : "v"(x));
  return r;
}

// ---------------------------------------------------------------- cast fp32->bf16
__global__ void cast_all(const float* __restrict__ x,  const float* __restrict__ wq,
                         const float* __restrict__ wk, const float* __restrict__ wv,
                         const float* __restrict__ wo,
                         __hip_bfloat16* __restrict__ xb,
                         __hip_bfloat16* __restrict__ wc,
                         __hip_bfloat16* __restrict__ wob) {
  const size_t M4 = (size_t)4 * 1024 * 1024;
  const size_t M1 = (size_t)1024 * 1024;
  size_t i = ((size_t)blockIdx.x * 256 + threadIdx.x) * 4;
  const float* src;
  __hip_bfloat16* dst;
  if (i < M4)                    { src = x  + i;                 dst = xb  + i; }
  else if (i < 2*M4)             { src = wq + (i - M4);          dst = wc  + (i - M4); }
  else if (i < 2*M4 + M1)        { src = wk + (i - 2*M4);        dst = wc  + M4 + (i - 2*M4); }
  else if (i < 2*M4 + 2*M1)      { src = wv + (i - 2*M4 - M1);   dst = wc  + M4 + M1 + (i - 2*M4 - M1); }
  else                           { src = wo + (i - 2*M4 - 2*M1); dst = wob + (i - 2*M4 - 2*M1); }
  float4 v = *reinterpret_cast<const float4*>(src);
  dst[0] = __float2bfloat16(v.x);
  dst[1] = __float2bfloat16(v.y);
  dst[2] = __float2bfloat16(v.z);
  dst[3] = __float2bfloat16(v.w);
}

// ---------------------------------------------------------------- GEMM  C = A * B^T
__global__ __launch_bounds__(256) void gemm_bt(const __hip_bfloat16* __restrict__ A,
                                               const __hip_bfloat16* __restrict__ B,
                                               float* __restrict__ C,
                                               int M, int N, int K) {
  __shared__ __hip_bfloat16 As[128 * 64];
  __shared__ __hip_bfloat16 Bs[128 * 64];
  const int nbc = N >> 7;
  const int br  = blockIdx.x / nbc;
  const int bc  = blockIdx.x % nbc;
  const int tid  = threadIdx.x;
  const int lane = tid & 63;
  const int w    = tid >> 6;
  const int wr   = w >> 1, wc = w & 1;
  const int l15  = lane & 15;
  const int fk   = (lane >> 4) << 3;

  f32x4 acc[4][4];
#pragma unroll
  for (int m = 0; m < 4; ++m)
#pragma unroll
    for (int n = 0; n < 4; ++n) acc[m][n] = (f32x4){0.f, 0.f, 0.f, 0.f};

  const __hip_bfloat16* Ag = A + (size_t)br * 128 * K;
  const __hip_bfloat16* Bg = B + (size_t)bc * 128 * K;

  int srow[4], scol[4];
#pragma unroll
  for (int r = 0; r < 4; ++r) {
    int o = (w * 4 + r) * 1024 + lane * 16;
    srow[r] = o >> 7;
    scol[r] = (o & 127) >> 1;
  }

  for (int kt = 0; kt < K; kt += 64) {
#pragma unroll
    for (int r = 0; r < 4; ++r) {
      const int c = w * 4 + r;
      gld16(Ag + (size_t)srow[r] * K + kt + scol[r], (char*)As + c * 1024);
      gld16(Bg + (size_t)srow[r] * K + kt + scol[r], (char*)Bs + c * 1024);
    }
    __syncthreads();

    bf16x8 a[4][2], b[4][2];
#pragma unroll
    for (int m = 0; m < 4; ++m)
#pragma unroll
      for (int kk = 0; kk < 2; ++kk)
        a[m][kk] = *reinterpret_cast<const bf16x8*>(
            (const char*)As + ((wr * 64 + m * 16 + l15) * 64 + kk * 32 + fk) * 2);
#pragma unroll
    for (int n = 0; n < 4; ++n)
#pragma unroll
      for (int kk = 0; kk < 2; ++kk)
        b[n][kk] = *reinterpret_cast<const bf16x8*>(
            (const char*)Bs + ((wc * 64 + n * 16 + l15) * 64 + kk * 32 + fk) * 2);

#pragma unroll
    for (int m = 0; m < 4; ++m)
#pragma unroll
      for (int n = 0; n < 4; ++n)
#pragma unroll
        for (int kk = 0; kk < 2; ++kk)
          acc[m][n] = __builtin_amdgcn_mfma_f32_16x16x32_bf16(a[m][kk], b[n][kk],
                                                              acc[m][n], 0, 0, 0);
    __syncthreads();
  }

  const int row0 = br * 128 + wr * 64;
  const int col0 = bc * 128 + wc * 64;
  const int rb   = (lane >> 4) * 4;
#pragma unroll
  for (int m = 0; m < 4; ++m)
#pragma unroll
    for (int n = 0; n < 4; ++n)
#pragma unroll
      for (int r = 0; r < 4; ++r)
        C[(size_t)(row0 + m * 16 + rb + r) * N + col0 + n * 16 + l15] = acc[m][n][r];
}

// ---------------------------------------------------------------- RoPE + cast to tiled fragment layouts
// Q gets 1/sqrt(HD) * log2(e) folded in (attention uses exp2-domain softmax).
// Tile-chunk ("TC") layouts, one 32-token tile = 2048 bf16 = 4KB:
//   K/Q: elem (t,d) -> tile (t>>5), chunk c = (d>>4)*64 + ((d>>3)&1)*32 + (t&31), byte elem d&7
//   V:   elem (d,t) -> tile (t>>5), chunk c = ((t>>4)&1)*128 + (d>>5)*64 + ((t>>3)&1)*32 + (d&31), elem t&7
// so that attn's per-lane 16B fragment loads are lane-consecutive (fully coalesced).
#define QSCALE 0.1803368801111243f   // 0.125 * log2(e)

__device__ __forceinline__ size_t kq_idx(int tile_row, int t, int d) {
  return ((size_t)tile_row) * 2048 +
         ((((d >> 4) * 64) + (((d >> 3) & 1) * 32) + (t & 31)) << 3) + (d & 7);
}

__global__ void rope_cast(const float* __restrict__ qkv,
                          const float* __restrict__ cosT, const float* __restrict__ sinT,
                          __hip_bfloat16* __restrict__ Qf,
                          __hip_bfloat16* __restrict__ Kf,
                          __hip_bfloat16* __restrict__ Vf) {
  const int QP = TOK * NH * (HD / 2);   // 2,097,152
  const int KP = TOK * NKV * (HD / 2);  //   524,288
  int idx = blockIdx.x * 256 + threadIdx.x;
  if (idx < QP) {
    int d = idx & 31, h = (idx >> 5) & 31, t = idx >> 10;
    const float* row = qkv + (size_t)t * QKVN + h * 64;
    float x1 = row[d], x2 = row[d + 32];
    float o1 = (x1 * cosT[t * 64 + d]      - x2 * sinT[t * 64 + d])      * QSCALE;
    float o2 = (x2 * cosT[t * 64 + d + 32] + x1 * sinT[t * 64 + d + 32]) * QSCALE;
    const int tile_row = h * 64 + (t >> 5);
    Qf[kq_idx(tile_row, t, d)]      = __float2bfloat16(o1);
    Qf[kq_idx(tile_row, t, d + 32)] = __float2bfloat16(o2);
  } else if (idx < QP + KP) {
    int j = idx - QP;
    int d = j & 31, hk = (j >> 5) & 7, t = j >> 8;
    const float* row = qkv + (size_t)t * QKVN + 2048 + hk * 64;
    float x1 = row[d], x2 = row[d + 32];
    float o1 = x1 * cosT[t * 64 + d]      - x2 * sinT[t * 64 + d];
    float o2 = x2 * cosT[t * 64 + d + 32] + x1 * sinT[t * 64 + d + 32];
    const int tile_row = hk * 64 + (t >> 5);
    Kf[kq_idx(tile_row, t, d)]      = __float2bfloat16(o1);
    Kf[kq_idx(tile_row, t, d + 32)] = __float2bfloat16(o2);
  } else {
    int vj = idx - QP - KP;               // d fastest -> coalesced qkv reads
    int d = vj & 63, t = (vj >> 6) & (TOK - 1), hk = vj >> 17;
    float v = qkv[(size_t)t * QKVN + 2560 + hk * 64 + d];
    const size_t tb = ((size_t)hk * 64 + (t >> 5)) * 2048;
    const int c = (((t >> 4) & 1) * 128) + ((d >> 5) * 64) + (((t >> 3) & 1) * 32) + (d & 31);
    Vf[tb + (c << 3) + (t & 7)] = __float2bfloat16(v);
  }
}

// ---------------------------------------------------------------- causal GQA flash attention
// 1 wave per block; swapped QK^T (S^T) + O^T accumulation; register-double-buffered
// K/V prefetch; exp2-domain online softmax; TC-layout coalesced fragment loads.
struct KVb { bf16x8 k0, k1, k2, k3, v00, v01, v10, v11; };

__device__ __forceinline__ void load_kv(KVb& b, const __hip_bfloat16* Kt,
                                        const __hip_bfloat16* Vt, int tile,
                                        int lane) {
  const __hip_bfloat16* Kp = Kt + (size_t)tile * 2048 + lane * 8;
  b.k0 = *reinterpret_cast<const bf16x8*>(Kp);
  b.k1 = *reinterpret_cast<const bf16x8*>(Kp + 512);
  b.k2 = *reinterpret_cast<const bf16x8*>(Kp + 1024);
  b.k3 = *reinterpret_cast<const bf16x8*>(Kp + 1536);
  const __hip_bfloat16* Vp = Vt + (size_t)tile * 2048 + lane * 8;
  b.v00 = *reinterpret_cast<const bf16x8*>(Vp);          // ks2=0, d 0..31
  b.v10 = *reinterpret_cast<const bf16x8*>(Vp + 512);    // ks2=0, d 32..63
  b.v01 = *reinterpret_cast<const bf16x8*>(Vp + 1024);   // ks2=1, d 0..31
  b.v11 = *reinterpret_cast<const bf16x8*>(Vp + 1536);   // ks2=1, d 32..63
}

__device__ __forceinline__ void compute_tile(const KVb& b, bool diag,
                                             const bf16x8 (&qf)[4],
                                             int l31, int hi,
                                             float& m, float& l,
                                             f32x16& oa0, f32x16& oa1) {
  f32x16 st;
#pragma unroll
  for (int r = 0; r < 16; ++r) st[r] = 0.f;
  st = __builtin_amdgcn_mfma_f32_32x32x16_bf16(b.k0, qf[0], st, 0, 0, 0);
  st = __builtin_amdgcn_mfma_f32_32x32x16_bf16(b.k1, qf[1], st, 0, 0, 0);
  st = __builtin_amdgcn_mfma_f32_32x32x16_bf16(b.k2, qf[2], st, 0, 0, 0);
  st = __builtin_amdgcn_mfma_f32_32x32x16_bf16(b.k3, qf[3], st, 0, 0, 0);

  float s[16];
#pragma unroll
  for (int r = 0; r < 16; ++r) s[r] = st[r];
  if (diag) {
#pragma unroll
    for (int r = 0; r < 16; ++r) {
      const int crow = (r & 3) + 8 * (r >> 2) + 4 * hi;   // kv offset in tile
      s[r] = (crow <= l31) ? s[r] : -1e30f;
    }
  }
  float t0 = fmaxf(fmaxf(s[0], s[1]),   fmaxf(s[2], s[3]));
  float t1 = fmaxf(fmaxf(s[4], s[5]),   fmaxf(s[6], s[7]));
  float t2 = fmaxf(fmaxf(s[8], s[9]),   fmaxf(s[10], s[11]));
  float t3 = fmaxf(fmaxf(s[12], s[13]), fmaxf(s[14], s[15]));
  float rmax = fmaxf(fmaxf(t0, t1), fmaxf(t2, t3));
  rmax = fmaxf(rmax, __shfl_xor(rmax, 32));
  const float mnew = fmaxf(m, rmax);
  const float resc = fexp2(m - mnew);      // exp2 domain (log2e folded into Q)
  float p[16];
#pragma unroll
  for (int r = 0; r < 16; ++r) p[r] = fexp2(s[r] - mnew);
  float u0 = (p[0] + p[1]) + (p[2] + p[3]);
  float u1 = (p[4] + p[5]) + (p[6] + p[7]);
  float u2 = (p[8] + p[9]) + (p[10] + p[11]);
  float u3 = (p[12] + p[13]) + (p[14] + p[15]);
  float rsum = (u0 + u1) + (u2 + u3);
  rsum += __shfl_xor(rsum, 32);
  l = l * resc + rsum;
  m = mnew;
#pragma unroll
  for (int r = 0; r < 16; ++r) { oa0[r] *= resc; oa1[r] *= resc; }

  // P -> bf16 B-frags in-register: 8 cvt_pk + 4 permlane32_swap
  unsigned int wpk[8];
#pragma unroll
  for (int j = 0; j < 8; ++j) wpk[j] = cvtpk_bf16(p[2 * j], p[2 * j + 1]);

  {
    unsigned int a0 = wpk[0], b0 = wpk[2];  pl32swap(a0, b0);
    unsigned int a1 = wpk[1], b1 = wpk[3];  pl32swap(a1, b1);
    u32x4 pw; pw[0] = a0; pw[1] = a1; pw[2] = b0; pw[3] = b1;
    bf16x8 pf = *reinterpret_cast<bf16x8*>(&pw);
    oa0 = __builtin_amdgcn_mfma_f32_32x32x16_bf16(b.v00, pf, oa0, 0, 0, 0);
    oa1 = __builtin_amdgcn_mfma_f32_32x32x16_bf16(b.v10, pf, oa1, 0, 0, 0);
  }
  {
    unsigned int a0 = wpk[4], b0 = wpk[6];  pl32swap(a0, b0);
    unsigned int a1 = wpk[5], b1 = wpk[7];  pl32swap(a1, b1);
    u32x4 pw; pw[0] = a0; pw[1] = a1; pw[2] = b0; pw[3] = b1;
    bf16x8 pf = *reinterpret_cast<bf16x8*>(&pw);
    oa0 = __builtin_amdgcn_mfma_f32_32x32x16_bf16(b.v01, pf, oa0, 0, 0, 0);
    oa1 = __builtin_amdgcn_mfma_f32_32x32x16_bf16(b.v11, pf, oa1, 0, 0, 0);
  }
}

// grid = 64 strips (desc) * 32 heads; block = 64 threads (1 wave, 32 q-rows)
__global__ __launch_bounds__(64) void attn3(const __hip_bfloat16* __restrict__ Qf,
                                            const __hip_bfloat16* __restrict__ Kf,
                                            const __hip_bfloat16* __restrict__ Vf,
                                            __hip_bfloat16* __restrict__ ctx) {
  const int h     = blockIdx.x & 31;
  const int strip = 63 - (blockIdx.x >> 5);       // longest blocks dispatch first
  const int hk    = h >> 2;
  const int lane  = threadIdx.x & 63;
  const int l31   = lane & 31, hi = lane >> 5;
  const int q0    = strip * 32;

  __shared__ float T[64][33];                     // epilogue transpose, padded

  const __hip_bfloat16* Kt = Kf + (size_t)hk * 64 * 2048;
  const __hip_bfloat16* Vt = Vf + (size_t)hk * 64 * 2048;

  // Q frags: TC layout, lane-consecutive 16B chunks (coalesced)
  const __hip_bfloat16* Qp = Qf + ((size_t)h * 64 + strip) * 2048 + lane * 8;
  bf16x8 qf[4];
#pragma unroll
  for (int ks = 0; ks < 4; ++ks)
    qf[ks] = *reinterpret_cast<const bf16x8*>(Qp + ks * 512);

  f32x16 oa0, oa1;
#pragma unroll
  for (int r = 0; r < 16; ++r) { oa0[r] = 0.f; oa1[r] = 0.f; }
  float m = -1e30f, l = 0.f;

  KVb A, B;
  load_kv(A, Kt, Vt, 0, lane);
  int kv = 0;
  for (;;) {
    int nxt = kv + 32;
    if (nxt <= q0) load_kv(B, Kt, Vt, nxt >> 5, lane);   // prefetch next tile
    compute_tile(A, kv == q0, qf, l31, hi, m, l, oa0, oa1);
    kv = nxt;
    if (kv > q0) break;
    nxt = kv + 32;
    if (nxt <= q0) load_kv(A, Kt, Vt, nxt >> 5, lane);
    compute_tile(B, kv == q0, qf, l31, hi, m, l, oa0, oa1);
    kv = nxt;
    if (kv > q0) break;
  }

  // epilogue: normalize, LDS untranspose, coalesced ctx write
  const float inv = 1.f / l;
#pragma unroll
  for (int r = 0; r < 16; ++r) {
    const int d = (r & 3) + 8 * (r >> 2) + 4 * hi;
    T[d][l31]      = oa0[r] * inv;
    T[d + 32][l31] = oa1[r] * inv;
  }
#pragma unroll 4
  for (int i = 0; i < 32; ++i) {
    const float v = T[lane][i];
    ctx[(size_t)(q0 + i) * EMB + h * HD + lane] = __float2bfloat16(v);
  }
}

// ---------------------------------------------------------------- launch
extern "C" void kernel_launch(void* const* d_in, const int* in_sizes, int n_in,
                              void* d_out, int out_size, void* d_ws, size_t ws_size,
                              hipStream_t stream) {
  const float* x    = (const float*)d_in[0];
  const float* cosT = (const float*)d_in[1];
  const float* sinT = (const float*)d_in[2];
  const float* Wq   = (const float*)d_in[3];
  const float* Wk   = (const float*)d_in[4];
  const float* Wv   = (const float*)d_in[5];
  const float* Wo   = (const float*)d_in[6];
  float* out = (float*)d_out;

  const size_t M4 = (size_t)4 * 1024 * 1024;
  const size_t M1 = (size_t)1024 * 1024;

  char* ws = (char*)d_ws;
  __hip_bfloat16* xb   = (__hip_bfloat16*)ws;
  __hip_bfloat16* Wc   = xb + M4;
  __hip_bfloat16* Wob  = Wc + (size_t)6 * M1;
  float*          qkv  = (float*)(Wob + M4);
  __hip_bfloat16* Qf   = (__hip_bfloat16*)(qkv + (size_t)TOK * QKVN);
  __hip_bfloat16* Kf   = Qf + (size_t)NH * TOK * HD;
  __hip_bfloat16* Vf   = Kf + (size_t)NKV * TOK * HD;
  __hip_bfloat16* ctxb = Vf + (size_t)NKV * HD * TOK;

  cast_all<<<14336, 256, 0, stream>>>(x, Wq, Wk, Wv, Wo, xb, Wc, Wob);

  // qkv = x @ Wqkv^T   (M=2048, N=3072, K=2048)
  gemm_bt<<<16 * 24, 256, 0, stream>>>(xb, Wc, qkv, TOK, QKVN, EMB);

  rope_cast<<<14336, 256, 0, stream>>>(qkv, cosT, sinT, Qf, Kf, Vf);

  // causal GQA attention: 1-wave blocks, strip-descending, coalesced TC loads
  attn3<<<64 * 32, 64, 0, stream>>>(Qf, Kf, Vf, ctxb);

  // out = ctx @ Wo^T   (M=N=K=2048)
  gemm_bt<<<16 * 16, 256, 0, stream>>>(ctxb, Wob, out, TOK, EMB, EMB);
}

// Round 5
// 145.982 us; speedup vs baseline: 1.8648x; 1.2025x over previous
//
#include <hip/hip_runtime.h>
#include <hip/hip_bf16.h>
#include <stdint.h>

#define EMB   2048
#define TOK   2048
#define NH    32
#define NKV   8
#define HD    64
#define QKVN  3072   // 2048 q + 512 k + 512 v

typedef __attribute__((ext_vector_type(8))) short bf16x8;   // 8 bf16 = 4 VGPRs
typedef __attribute__((ext_vector_type(4))) float f32x4;
typedef __attribute__((ext_vector_type(16))) float f32x16;
typedef __attribute__((ext_vector_type(4))) unsigned int u32x4;

__device__ __forceinline__ void gld16(const void* g, void* l) {
  auto gp = reinterpret_cast<const int __attribute__((address_space(1)))*>(
      reinterpret_cast<uintptr_t>(g));
  auto lp = reinterpret_cast<int __attribute__((address_space(3)))*>(
      reinterpret_cast<uintptr_t>(l));
  __builtin_amdgcn_global_load_lds(gp, lp, 16, 0, 0);
}

__device__ __forceinline__ unsigned int cvtpk_bf16(float lo, float hi) {
  unsigned int r;
  asm("v_cvt_pk_bf16_f32 %0, %1, %2" : "=v"(r) : "v"(lo), "v"(hi));
  return r;
}
// v_permlane32_swap_b32 vdst, vsrc: after, vdst=[dst.lo|src.lo], vsrc=[dst.hi|src.hi]
__device__ __forceinline__ void pl32swap(unsigned int &a, unsigned int &b) {
  asm volatile("v_permlane32_swap_b32 %0, %1" : "+v"(a), "+v"(b));
}
__device__ __forceinline__ float fexp2(float x) {  // v_exp_f32 IS 2^x
  float r;
  asm("v_exp_f32 %0, %1" : "=v"(r) : "v"(x));
  return r;
}

// ---------------------------------------------------------------- cast fp32->bf16
__global__ void cast_all(const float* __restrict__ x,  const float* __restrict__ wq,
                         const float* __restrict__ wk, const float* __restrict__ wv,
                         const float* __restrict__ wo,
                         __hip_bfloat16* __restrict__ xb,
                         __hip_bfloat16* __restrict__ wc,
                         __hip_bfloat16* __restrict__ wob) {
  const size_t M4 = (size_t)4 * 1024 * 1024;
  const size_t M1 = (size_t)1024 * 1024;
  size_t i = ((size_t)blockIdx.x * 256 + threadIdx.x) * 4;
  const float* src;
  __hip_bfloat16* dst;
  if (i < M4)                    { src = x  + i;                 dst = xb  + i; }
  else if (i < 2*M4)             { src = wq + (i - M4);          dst = wc  + (i - M4); }
  else if (i < 2*M4 + M1)        { src = wk + (i - 2*M4);        dst = wc  + M4 + (i - 2*M4); }
  else if (i < 2*M4 + 2*M1)      { src = wv + (i - 2*M4 - M1);   dst = wc  + M4 + M1 + (i - 2*M4 - M1); }
  else                           { src = wo + (i - 2*M4 - 2*M1); dst = wob + (i - 2*M4 - 2*M1); }
  float4 v = *reinterpret_cast<const float4*>(src);
  dst[0] = __float2bfloat16(v.x);
  dst[1] = __float2bfloat16(v.y);
  dst[2] = __float2bfloat16(v.z);
  dst[3] = __float2bfloat16(v.w);
}

// ---------------------------------------------------------------- GEMM  C = A * B^T
// 128x128 tile, BK=64, 4 waves; double-buffered LDS, 2-phase pipeline:
// stage(t+1) issued BEFORE compute(t); single vmcnt-drain barrier per K-step.
__global__ __launch_bounds__(256) void gemm_bt(const __hip_bfloat16* __restrict__ A,
                                               const __hip_bfloat16* __restrict__ B,
                                               float* __restrict__ C,
                                               int M, int N, int K) {
  __shared__ __hip_bfloat16 As[2][128 * 64];
  __shared__ __hip_bfloat16 Bs[2][128 * 64];
  const int nbc = N >> 7;
  const int br  = blockIdx.x / nbc;
  const int bc  = blockIdx.x % nbc;
  const int tid  = threadIdx.x;
  const int lane = tid & 63;
  const int w    = tid >> 6;
  const int wr   = w >> 1, wc = w & 1;
  const int l15  = lane & 15;
  const int fk   = (lane >> 4) << 3;

  f32x4 acc[4][4];
#pragma unroll
  for (int m = 0; m < 4; ++m)
#pragma unroll
    for (int n = 0; n < 4; ++n) acc[m][n] = (f32x4){0.f, 0.f, 0.f, 0.f};

  const __hip_bfloat16* Ag = A + (size_t)br * 128 * K;
  const __hip_bfloat16* Bg = B + (size_t)bc * 128 * K;

  int srow[4], scol[4];
#pragma unroll
  for (int r = 0; r < 4; ++r) {
    int o = (w * 4 + r) * 1024 + lane * 16;
    srow[r] = o >> 7;
    scol[r] = (o & 127) >> 1;
  }

  auto stage = [&](int buf, int kt) {
#pragma unroll
    for (int r = 0; r < 4; ++r) {
      const int c = w * 4 + r;
      gld16(Ag + (size_t)srow[r] * K + kt + scol[r], (char*)As + buf * 16384 + c * 1024);
      gld16(Bg + (size_t)srow[r] * K + kt + scol[r], (char*)Bs + buf * 16384 + c * 1024);
    }
  };
  auto compute = [&](int buf) {
    bf16x8 a[4][2], b[4][2];
#pragma unroll
    for (int m = 0; m < 4; ++m)
#pragma unroll
      for (int kk = 0; kk < 2; ++kk)
        a[m][kk] = *reinterpret_cast<const bf16x8*>(
            (const char*)As + buf * 16384 + ((wr * 64 + m * 16 + l15) * 64 + kk * 32 + fk) * 2);
#pragma unroll
    for (int n = 0; n < 4; ++n)
#pragma unroll
      for (int kk = 0; kk < 2; ++kk)
        b[n][kk] = *reinterpret_cast<const bf16x8*>(
            (const char*)Bs + buf * 16384 + ((wc * 64 + n * 16 + l15) * 64 + kk * 32 + fk) * 2);
#pragma unroll
    for (int m = 0; m < 4; ++m)
#pragma unroll
      for (int n = 0; n < 4; ++n)
#pragma unroll
        for (int kk = 0; kk < 2; ++kk)
          acc[m][n] = __builtin_amdgcn_mfma_f32_16x16x32_bf16(a[m][kk], b[n][kk],
                                                              acc[m][n], 0, 0, 0);
  };

  stage(0, 0);
  __syncthreads();                 // drain prologue stage
  int cur = 0;
  int kt = 0;
  for (; kt < K - 64; kt += 64) {
    stage(cur ^ 1, kt + 64);       // prefetch flies under compute
    compute(cur);
    __syncthreads();               // vmcnt(0)+barrier: prefetch ready, LDS reads done
    cur ^= 1;
  }
  compute(cur);                    // last tile, no prefetch

  const int row0 = br * 128 + wr * 64;
  const int col0 = bc * 128 + wc * 64;
  const int rb   = (lane >> 4) * 4;
#pragma unroll
  for (int m = 0; m < 4; ++m)
#pragma unroll
    for (int n = 0; n < 4; ++n)
#pragma unroll
      for (int r = 0; r < 4; ++r)
        C[(size_t)(row0 + m * 16 + rb + r) * N + col0 + n * 16 + l15] = acc[m][n][r];
}

// ---------------------------------------------------------------- RoPE + cast to tiled fragment layouts
// Q gets 1/sqrt(HD) * log2(e) folded in (attention uses exp2-domain softmax).
// Tile-chunk ("TC") layouts, one 32-token tile = 2048 bf16 = 4KB:
//   K/Q: elem (t,d) -> tile (t>>5), chunk c = (d>>4)*64 + ((d>>3)&1)*32 + (t&31), byte elem d&7
//   V:   elem (d,t) -> tile (t>>5), chunk c = ((t>>4)&1)*128 + (d>>5)*64 + ((t>>3)&1)*32 + (d&31), elem t&7
#define QSCALE 0.1803368801111243f   // 0.125 * log2(e)

__device__ __forceinline__ size_t kq_idx(int tile_row, int t, int d) {
  return ((size_t)tile_row) * 2048 +
         ((((d >> 4) * 64) + (((d >> 3) & 1) * 32) + (t & 31)) << 3) + (d & 7);
}

__global__ void rope_cast(const float* __restrict__ qkv,
                          const float* __restrict__ cosT, const float* __restrict__ sinT,
                          __hip_bfloat16* __restrict__ Qf,
                          __hip_bfloat16* __restrict__ Kf,
                          __hip_bfloat16* __restrict__ Vf) {
  const int QP = TOK * NH * (HD / 2);   // 2,097,152
  const int KP = TOK * NKV * (HD / 2);  //   524,288
  int idx = blockIdx.x * 256 + threadIdx.x;
  if (idx < QP) {
    int d = idx & 31, h = (idx >> 5) & 31, t = idx >> 10;
    const float* row = qkv + (size_t)t * QKVN + h * 64;
    float x1 = row[d], x2 = row[d + 32];
    float o1 = (x1 * cosT[t * 64 + d]      - x2 * sinT[t * 64 + d])      * QSCALE;
    float o2 = (x2 * cosT[t * 64 + d + 32] + x1 * sinT[t * 64 + d + 32]) * QSCALE;
    const int tile_row = h * 64 + (t >> 5);
    Qf[kq_idx(tile_row, t, d)]      = __float2bfloat16(o1);
    Qf[kq_idx(tile_row, t, d + 32)] = __float2bfloat16(o2);
  } else if (idx < QP + KP) {
    int j = idx - QP;
    int d = j & 31, hk = (j >> 5) & 7, t = j >> 8;
    const float* row = qkv + (size_t)t * QKVN + 2048 + hk * 64;
    float x1 = row[d], x2 = row[d + 32];
    float o1 = x1 * cosT[t * 64 + d]      - x2 * sinT[t * 64 + d];
    float o2 = x2 * cosT[t * 64 + d + 32] + x1 * sinT[t * 64 + d + 32];
    const int tile_row = hk * 64 + (t >> 5);
    Kf[kq_idx(tile_row, t, d)]      = __float2bfloat16(o1);
    Kf[kq_idx(tile_row, t, d + 32)] = __float2bfloat16(o2);
  } else {
    int vj = idx - QP - KP;               // d fastest -> coalesced qkv reads
    int d = vj & 63, t = (vj >> 6) & (TOK - 1), hk = vj >> 17;
    float v = qkv[(size_t)t * QKVN + 2560 + hk * 64 + d];
    const size_t tb = ((size_t)hk * 64 + (t >> 5)) * 2048;
    const int c = (((t >> 4) & 1) * 128) + ((d >> 5) * 64) + (((t >> 3) & 1) * 32) + (d & 31);
    Vf[tb + (c << 3) + (t & 7)] = __float2bfloat16(v);
  }
}

// ---------------------------------------------------------------- causal GQA flash attention
// 4-way kv-split per block (flash-decoding in-LDS): 256 threads = 4 waves, each
// wave computes partial (oa,m,l) over kv tiles {w, w+4, ...}; merge in LDS.
// Swapped QK^T + O^T accumulation, register dbuf prefetch, exp2 softmax,
// defer-max (THR=8 log2 units), TC-layout coalesced loads.
struct KVb { bf16x8 k0, k1, k2, k3, v00, v01, v10, v11; };

__device__ __forceinline__ void load_kv(KVb& b, const __hip_bfloat16* Kt,
                                        const __hip_bfloat16* Vt, int tile,
                                        int lane) {
  const __hip_bfloat16* Kp = Kt + (size_t)tile * 2048 + lane * 8;
  b.k0 = *reinterpret_cast<const bf16x8*>(Kp);
  b.k1 = *reinterpret_cast<const bf16x8*>(Kp + 512);
  b.k2 = *reinterpret_cast<const bf16x8*>(Kp + 1024);
  b.k3 = *reinterpret_cast<const bf16x8*>(Kp + 1536);
  const __hip_bfloat16* Vp = Vt + (size_t)tile * 2048 + lane * 8;
  b.v00 = *reinterpret_cast<const bf16x8*>(Vp);          // ks2=0, d 0..31
  b.v10 = *reinterpret_cast<const bf16x8*>(Vp + 512);    // ks2=0, d 32..63
  b.v01 = *reinterpret_cast<const bf16x8*>(Vp + 1024);   // ks2=1, d 0..31
  b.v11 = *reinterpret_cast<const bf16x8*>(Vp + 1536);   // ks2=1, d 32..63
}

__device__ __forceinline__ void compute_tile(const KVb& b, bool diag,
                                             const bf16x8 (&qf)[4],
                                             int l31, int hi,
                                             float& m, float& l,
                                             f32x16& oa0, f32x16& oa1) {
  f32x16 st;
#pragma unroll
  for (int r = 0; r < 16; ++r) st[r] = 0.f;
  st = __builtin_amdgcn_mfma_f32_32x32x16_bf16(b.k0, qf[0], st, 0, 0, 0);
  st = __builtin_amdgcn_mfma_f32_32x32x16_bf16(b.k1, qf[1], st, 0, 0, 0);
  st = __builtin_amdgcn_mfma_f32_32x32x16_bf16(b.k2, qf[2], st, 0, 0, 0);
  st = __builtin_amdgcn_mfma_f32_32x32x16_bf16(b.k3, qf[3], st, 0, 0, 0);

  float s[16];
#pragma unroll
  for (int r = 0; r < 16; ++r) s[r] = st[r];
  if (diag) {
#pragma unroll
    for (int r = 0; r < 16; ++r) {
      const int crow = (r & 3) + 8 * (r >> 2) + 4 * hi;   // kv offset in tile
      s[r] = (crow <= l31) ? s[r] : -1e30f;
    }
  }
  float t0 = fmaxf(fmaxf(s[0], s[1]),   fmaxf(s[2], s[3]));
  float t1 = fmaxf(fmaxf(s[4], s[5]),   fmaxf(s[6], s[7]));
  float t2 = fmaxf(fmaxf(s[8], s[9]),   fmaxf(s[10], s[11]));
  float t3 = fmaxf(fmaxf(s[12], s[13]), fmaxf(s[14], s[15]));
  float rmax = fmaxf(fmaxf(t0, t1), fmaxf(t2, t3));
  rmax = fmaxf(rmax, __shfl_xor(rmax, 32));

  // defer-max (T13): skip rescale when per-col max grew by <= 8 (log2 units;
  // P then bounded by 2^8=256, fine in fp32 accum / bf16 P).
  const int allskip = __all(rmax <= m + 8.0f);
  const float mnew = allskip ? m : fmaxf(m, rmax);
  float p[16];
#pragma unroll
  for (int r = 0; r < 16; ++r) p[r] = fexp2(s[r] - mnew);
  float u0 = (p[0] + p[1]) + (p[2] + p[3]);
  float u1 = (p[4] + p[5]) + (p[6] + p[7]);
  float u2 = (p[8] + p[9]) + (p[10] + p[11]);
  float u3 = (p[12] + p[13]) + (p[14] + p[15]);
  float rsum = (u0 + u1) + (u2 + u3);
  rsum += __shfl_xor(rsum, 32);
  if (!allskip) {
    const float resc = fexp2(m - mnew);
    l *= resc;
    m = mnew;
#pragma unroll
    for (int r = 0; r < 16; ++r) { oa0[r] *= resc; oa1[r] *= resc; }
  }
  l += rsum;

  // P -> bf16 B-frags in-register: 8 cvt_pk + 4 permlane32_swap
  unsigned int wpk[8];
#pragma unroll
  for (int j = 0; j < 8; ++j) wpk[j] = cvtpk_bf16(p[2 * j], p[2 * j + 1]);

  {
    unsigned int a0 = wpk[0], b0 = wpk[2];  pl32swap(a0, b0);
    unsigned int a1 = wpk[1], b1 = wpk[3];  pl32swap(a1, b1);
    u32x4 pw; pw[0] = a0; pw[1] = a1; pw[2] = b0; pw[3] = b1;
    bf16x8 pf = *reinterpret_cast<bf16x8*>(&pw);
    oa0 = __builtin_amdgcn_mfma_f32_32x32x16_bf16(b.v00, pf, oa0, 0, 0, 0);
    oa1 = __builtin_amdgcn_mfma_f32_32x32x16_bf16(b.v10, pf, oa1, 0, 0, 0);
  }
  {
    unsigned int a0 = wpk[4], b0 = wpk[6];  pl32swap(a0, b0);
    unsigned int a1 = wpk[5], b1 = wpk[7];  pl32swap(a1, b1);
    u32x4 pw; pw[0] = a0; pw[1] = a1; pw[2] = b0; pw[3] = b1;
    bf16x8 pf = *reinterpret_cast<bf16x8*>(&pw);
    oa0 = __builtin_amdgcn_mfma_f32_32x32x16_bf16(b.v01, pf, oa0, 0, 0, 0);
    oa1 = __builtin_amdgcn_mfma_f32_32x32x16_bf16(b.v11, pf, oa1, 0, 0, 0);
  }
}

// grid = 64 strips (desc) * 32 heads; block = 256 (4 waves = 4 kv-splits)
__global__ __launch_bounds__(256) void attn4(const __hip_bfloat16* __restrict__ Qf,
                                             const __hip_bfloat16* __restrict__ Kf,
                                             const __hip_bfloat16* __restrict__ Vf,
                                             __hip_bfloat16* __restrict__ ctx) {
  const int h     = blockIdx.x & 31;
  const int strip = 63 - (blockIdx.x >> 5);       // longest blocks dispatch first
  const int hk    = h >> 2;
  const int tid   = threadIdx.x;
  const int w     = tid >> 6;                     // kv-split index 0..3
  const int lane  = tid & 63;
  const int l31   = lane & 31, hi = lane >> 5;
  const int q0    = strip * 32;
  const int nt    = strip + 1;                    // kv tiles for this strip

  __shared__ float part[4][64][33];               // partial O^T per split (padded)
  __shared__ float mlb[4][2][32];                 // m,l per split per q-col

  const __hip_bfloat16* Kt = Kf + (size_t)hk * 64 * 2048;
  const __hip_bfloat16* Vt = Vf + (size_t)hk * 64 * 2048;

  const __hip_bfloat16* Qp = Qf + ((size_t)h * 64 + strip) * 2048 + lane * 8;
  bf16x8 qf[4];
#pragma unroll
  for (int ks = 0; ks < 4; ++ks)
    qf[ks] = *reinterpret_cast<const bf16x8*>(Qp + ks * 512);

  f32x16 oa0, oa1;
#pragma unroll
  for (int r = 0; r < 16; ++r) { oa0[r] = 0.f; oa1[r] = 0.f; }
  float m = -1e30f, l = 0.f;

  if (w < nt) {                                   // wave-uniform
    KVb A, B;
    load_kv(A, Kt, Vt, w, lane);
    int t = w;
    for (;;) {
      int nx = t + 4;
      if (nx < nt) load_kv(B, Kt, Vt, nx, lane);  // prefetch
      compute_tile(A, t == nt - 1, qf, l31, hi, m, l, oa0, oa1);
      t = nx;
      if (t >= nt) break;
      nx = t + 4;
      if (nx < nt) load_kv(A, Kt, Vt, nx, lane);
      compute_tile(B, t == nt - 1, qf, l31, hi, m, l, oa0, oa1);
      t = nx;
      if (t >= nt) break;
    }
  }

  // ---- write partials to LDS
#pragma unroll
  for (int r = 0; r < 16; ++r) {
    const int d = (r & 3) + 8 * (r >> 2) + 4 * hi;
    part[w][d][l31]      = oa0[r];
    part[w][d + 32][l31] = oa1[r];
  }
  if (hi == 0) { mlb[w][0][l31] = m; mlb[w][1][l31] = l; }
  __syncthreads();

  // ---- merge 4 partials + write ctx (coalesced: lanes span d)
  const int d  = tid & 63;
  const int qg = tid >> 6;
#pragma unroll
  for (int qq = 0; qq < 8; ++qq) {
    const int q = qg * 8 + qq;
    const float m0 = mlb[0][0][q], m1 = mlb[1][0][q];
    const float m2 = mlb[2][0][q], m3 = mlb[3][0][q];
    const float M = fmaxf(fmaxf(m0, m1), fmaxf(m2, m3));
    const float s0 = fexp2(m0 - M), s1 = fexp2(m1 - M);
    const float s2 = fexp2(m2 - M), s3 = fexp2(m3 - M);
    const float L = mlb[0][1][q] * s0 + mlb[1][1][q] * s1 +
                    mlb[2][1][q] * s2 + mlb[3][1][q] * s3;
    const float val = part[0][d][q] * s0 + part[1][d][q] * s1 +
                      part[2][d][q] * s2 + part[3][d][q] * s3;
    ctx[(size_t)(q0 + q) * EMB + h * HD + d] = __float2bfloat16(val / L);
  }
}

// ---------------------------------------------------------------- launch
extern "C" void kernel_launch(void* const* d_in, const int* in_sizes, int n_in,
                              void* d_out, int out_size, void* d_ws, size_t ws_size,
                              hipStream_t stream) {
  const float* x    = (const float*)d_in[0];
  const float* cosT = (const float*)d_in[1];
  const float* sinT = (const float*)d_in[2];
  const float* Wq   = (const float*)d_in[3];
  const float* Wk   = (const float*)d_in[4];
  const float* Wv   = (const float*)d_in[5];
  const float* Wo   = (const float*)d_in[6];
  float* out = (float*)d_out;

  const size_t M4 = (size_t)4 * 1024 * 1024;
  const size_t M1 = (size_t)1024 * 1024;

  char* ws = (char*)d_ws;
  __hip_bfloat16* xb   = (__hip_bfloat16*)ws;
  __hip_bfloat16* Wc   = xb + M4;
  __hip_bfloat16* Wob  = Wc + (size_t)6 * M1;
  float*          qkv  = (float*)(Wob + M4);
  __hip_bfloat16* Qf   = (__hip_bfloat16*)(qkv + (size_t)TOK * QKVN);
  __hip_bfloat16* Kf   = Qf + (size_t)NH * TOK * HD;
  __hip_bfloat16* Vf   = Kf + (size_t)NKV * TOK * HD;
  __hip_bfloat16* ctxb = Vf + (size_t)NKV * HD * TOK;

  cast_all<<<14336, 256, 0, stream>>>(x, Wq, Wk, Wv, Wo, xb, Wc, Wob);

  // qkv = x @ Wqkv^T   (M=2048, N=3072, K=2048)
  gemm_bt<<<16 * 24, 256, 0, stream>>>(xb, Wc, qkv, TOK, QKVN, EMB);

  rope_cast<<<14336, 256, 0, stream>>>(qkv, cosT, sinT, Qf, Kf, Vf);

  // causal GQA attention: 4-way kv-split blocks, strip-descending
  attn4<<<64 * 32, 256, 0, stream>>>(Qf, Kf, Vf, ctxb);

  // out = ctx @ Wo^T   (M=N=K=2048)
  gemm_bt<<<16 * 16, 256, 0, stream>>>(ctxb, Wob, out, TOK, EMB, EMB);
}